// Round 9
// baseline (339.801 us; speedup 1.0000x reference)
//
#include <hip/hip_runtime.h>
#include <hip/hip_bf16.h>

// IO-HMM fwd/bwd chain + projection for MI355X (gfx950).
// L=256 steps, B=128 batch, S=256 states, NL=64 labels.
//
// Kernel 1 (chain): 16 blocks (8 fwd, 8 bwd) x 512 threads (8 waves).
//   Wave w owns 32 states; T as f16 A-frags: a_hi=f16(T), a_lo=f16((T-hi)*2048)
//   (scaled so lo avoids f16-denormal flush); acc = hh + lh/2048 -> T to 2^-22.
//   Carry (16 b x 256 k) in LDS, double-buffered single-f16 plane, row
//   stride 67 x 8B (odd -> 0 bank conflicts, R5/R6-verified).
//   Step body: [ds_reads | global store(prev) + em/tok prefetch under read
//   shadow | MFMA | combine+pack | ds_write | lds-only barrier]; 2-step
//   unroll w/ compile-time parity; fw/g stored f16.
//   R8 ERRATUM: pack MUST be RNE. v_cvt_pkrtz is round-toward-zero; its
//   -2^-12 mean bias compounds coherently over 255 chain steps -> ~6%
//   systematic shrink (absmax 1792 = 9% of ref max). RNE casts restore the
//   unbiased random walk (R6: absmax 64).
// Kernel 2 (score): f16 end-to-end: p = fw*g via v_pk_mul_f16 (RNE), single
//   LDS plane, outm as f16 hi + scaled-lo (2 products).

typedef _Float16 half8 __attribute__((ext_vector_type(8)));
typedef _Float16 half4 __attribute__((ext_vector_type(4)));
typedef float    f32x4 __attribute__((ext_vector_type(4)));
typedef unsigned long long u64;

#define LL 256
#define BB 128
#define SS 256
#define BT 16
#define RSTR8 67   // LDS row stride in 8B units (ODD -> conflict-free, verified)
#define LO_SCALE 2048.0f
#define LO_UNSCALE 4.8828125e-4f

static __device__ __forceinline__ f32x4 mfma16f(half8 a, half8 b, f32x4 c) {
  return __builtin_amdgcn_mfma_f32_16x16x32_f16(a, b, c, 0, 0, 0);
}

// LDS-only barrier: order ds ops, leave vmcnt (global loads/stores) in flight.
static __device__ __forceinline__ void lds_barrier() {
  __asm__ __volatile__("s_waitcnt lgkmcnt(0)\n\ts_barrier" ::: "memory");
}

// Round-to-nearest-even f16 pack (NOT cvt_pkrtz -- RTZ bias compounds over
// the 255-step chain; see R8 erratum above).
static __device__ __forceinline__ u64 pack4(f32x4 v) {
  union { half4 h; u64 u; } x;
  x.h[0] = (_Float16)v[0];
  x.h[1] = (_Float16)v[1];
  x.h[2] = (_Float16)v[2];
  x.h[3] = (_Float16)v[3];
  return x.u;
}

static __device__ __forceinline__ half8 read_frag_h(const u64* plane, int m, int kt, int q) {
  const int o = m * RSTR8 + kt * 8 + q * 2;
  union { u64 u[2]; half8 v; } x;
  x.u[0] = plane[o];
  x.u[1] = plane[o + 1];
  return x.v;
}

// One chain step. RB = read-buffer parity (compile-time). Consumes EMC
// (em for this step) and TOKC (token for next step's em row); produces
// EMN/TOKN (for next body) and SVN (this step's f16-packed output pair).
// Stores SVC (previous step's output) under the ds_read shadow.
#define CHAIN_STEP(RB, EMC, EMN, TOKC, TOKN, SVC, SVN, DO_STORE)               \
  {                                                                            \
    const u64* cb = &s_carry[RB][0];                                           \
    half8 bfr[8];                                                              \
    _Pragma("unroll")                                                          \
    for (int kt = 0; kt < 8; ++kt) bfr[kt] = read_frag_h(cb, m, kt, q);        \
    if (DO_STORE) {                                                            \
      *(u64*)(optr)      = SVC[0];                                             \
      *(u64*)(optr + 16) = SVC[1];                                             \
      optr += dl;                                                              \
    }                                                                          \
    EMN[0] = *(const f32x4*)(emb + (size_t)TOKC * 256 + 32 * w + 4 * q);       \
    EMN[1] = *(const f32x4*)(emb + (size_t)TOKC * 256 + 32 * w + 16 + 4 * q);  \
    TOKN = sent_row[tl];                                                       \
    tl = fwd ? (tl < LL - 1 ? tl + 1 : LL - 1) : (tl > 0 ? tl - 1 : 0);        \
    f32x4 hh0 = 0.0f, lh0 = 0.0f, hh1 = 0.0f, lh1 = 0.0f;                      \
    _Pragma("unroll")                                                          \
    for (int kt = 0; kt < 8; ++kt) {                                           \
      hh0 = mfma16f(a_hi[0][kt], bfr[kt], hh0);                                \
      hh1 = mfma16f(a_hi[1][kt], bfr[kt], hh1);                                \
      lh0 = mfma16f(a_lo[0][kt], bfr[kt], lh0);                                \
      lh1 = mfma16f(a_lo[1][kt], bfr[kt], lh1);                                \
    }                                                                          \
    f32x4 v0 = hh0 + lh0 * LO_UNSCALE;                                         \
    f32x4 v1 = hh1 + lh1 * LO_UNSCALE;                                         \
    f32x4 c0 = v0 * EMC[0];                                                    \
    f32x4 c1 = v1 * EMC[1];                                                    \
    u64 p0 = pack4(c0), p1 = pack4(c1);                                        \
    u64* wbuf = &s_carry[RB ^ 1][0];                                           \
    wbuf[m * RSTR8 + 8 * w + q]     = p0;                                      \
    wbuf[m * RSTR8 + 8 * w + 4 + q] = p1;                                      \
    SVN[0] = fwd ? p0 : pack4(v0);                                             \
    SVN[1] = fwd ? p1 : pack4(v1);                                             \
    lds_barrier();                                                             \
  }

__global__ __launch_bounds__(512, 2)
void hmm_chain(const int* __restrict__ sent, const float* __restrict__ emb,
               const float* __restrict__ T, _Float16* __restrict__ fwh,
               _Float16* __restrict__ gh)
{
  __shared__ u64 s_carry[2][BT * RSTR8]; // [buf][row*stride], single f16 plane

  const int tid  = threadIdx.x;
  const int lane = tid & 63;
  const int w    = tid >> 6;   // wave 0..7 -> states [32w, 32w+32)
  const int m    = lane & 15;  // A row-in-tile / B col (= batch)
  const int q    = lane >> 4;  // quad

  const int  bid = blockIdx.x;
  const bool fwd = (bid < 8);
  const int  bg0 = (fwd ? bid : bid - 8) * BT;
  _Float16* const obuf = fwd ? fwh : gh;
  const int* const sent_row = sent + (size_t)(bg0 + m) * LL;

  // ---- load T fragments (A operand), f16 hi + scaled-lo: 32 frags = 128 regs
  half8 a_hi[2][8], a_lo[2][8];
#pragma unroll
  for (int mt = 0; mt < 2; ++mt) {
#pragma unroll
    for (int kt = 0; kt < 8; ++kt) {
      const int r0 = 32 * w + 16 * mt + m;   // state (M index)
      const int kb = 32 * kt + 8 * q;        // k base
      float v[8];
      if (fwd) {
        f32x4 f0 = *(const f32x4*)(T + r0 * 256 + kb);
        f32x4 f1 = *(const f32x4*)(T + r0 * 256 + kb + 4);
#pragma unroll
        for (int j = 0; j < 4; ++j) { v[j] = f0[j]; v[4 + j] = f1[j]; }
      } else {
#pragma unroll
        for (int j = 0; j < 8; ++j) v[j] = T[(kb + j) * 256 + r0]; // T^T
      }
      half8 hi, lo;
#pragma unroll
      for (int j = 0; j < 8; ++j) {
        _Float16 h = (_Float16)v[j];
        hi[j] = h;
        lo[j] = (_Float16)((v[j] - (float)h) * LO_SCALE);
      }
      a_hi[mt][kt] = hi; a_lo[mt][kt] = lo;
    }
  }

  // ---- init carry at l0 + first-row store ----
  const int l0 = fwd ? 0 : (LL - 1);
  {
    const int tok0 = sent_row[l0];
#pragma unroll
    for (int mt = 0; mt < 2; ++mt) {
      const int st = 32 * w + 16 * mt + 4 * q;
      f32x4 e0 = *(const f32x4*)(emb + (size_t)tok0 * 256 + st);
      u64 pc = pack4(e0);                       // carry = em[l0] both dirs
      f32x4 one = 1.0f;
      u64 po = fwd ? pc : pack4(one);           // g[L-1] = 1
      *(u64*)(obuf + (size_t)(l0 * BB + bg0 + m) * SS + st) = po;
      s_carry[0][m * RSTR8 + 8 * w + 4 * mt + q] = pc;
    }
  }

  // ---- prefetch em for step 1, token for step 2; running store pointer ----
  const int l1 = fwd ? 1 : (LL - 2);
  f32x4 em_a[2], em_b[2];
  {
    const int tok1 = sent_row[l1];
    em_a[0] = *(const f32x4*)(emb + (size_t)tok1 * 256 + 32 * w + 4 * q);
    em_a[1] = *(const f32x4*)(emb + (size_t)tok1 * 256 + 32 * w + 16 + 4 * q);
  }
  int tok_a = sent_row[fwd ? 2 : LL - 3];    // token for em of step 2
  int tok_b;
  int tl = fwd ? 3 : LL - 4;                 // next token index to read (step 3's em)
  const int dl = fwd ? BB * SS : -(BB * SS); // store-pointer advance (halfs)
  _Float16* optr = obuf + (size_t)(l1 * BB + bg0 + m) * SS + 32 * w + 4 * q;
  u64 sv_a[2], sv_b[2];
  __syncthreads();

  // ---- main chain: peeled s=1, then 127 pairs (s=2..255) ----
  CHAIN_STEP(0, em_a, em_b, tok_a, tok_b, sv_b, sv_a, 0)
  for (int sp = 0; sp < 127; ++sp) {
    CHAIN_STEP(1, em_b, em_a, tok_b, tok_a, sv_a, sv_b, 1)
    CHAIN_STEP(0, em_a, em_b, tok_a, tok_b, sv_b, sv_a, 1)
  }
  // final store: sv(255) (odd step -> sv_a), at l(255)
  *(u64*)(optr)      = sv_a[0];
  *(u64*)(optr + 16) = sv_a[1];
}

__global__ __launch_bounds__(256, 2)
void hmm_score(const _Float16* __restrict__ fwh, const _Float16* __restrict__ gh,
               const float* __restrict__ outm, float* __restrict__ score)
{
  __shared__ u64 p_pl[64 * RSTR8];

  const int tid  = threadIdx.x;
  const int lane = tid & 63;
  const int w    = tid >> 6;
  const int rh   = w >> 1;     // row half: rows [32rh, 32rh+32)
  const int np   = w & 1;      // n-pair: n-tiles {2np, 2np+1}
  const int m    = lane & 15;
  const int q    = lane >> 4;
  const int R0   = blockIdx.x * 64;  // row = l*128 + b

  // out-matrix fragments, f16 hi + scaled lo, this wave's 2 n-tiles
  half8 o_hi[8][2], o_lo[8][2];
#pragma unroll
  for (int kt = 0; kt < 8; ++kt) {
#pragma unroll
    for (int jn = 0; jn < 2; ++jn) {
      half8 hi, lo;
#pragma unroll
      for (int j = 0; j < 8; ++j) {
        float vv = outm[(32 * kt + 8 * q + j) * 64 + 16 * (2 * np + jn) + m];
        _Float16 h = (_Float16)vv;
        hi[j] = h;
        lo[j] = (_Float16)((vv - (float)h) * LO_SCALE);
      }
      o_hi[kt][jn] = hi; o_lo[kt][jn] = lo;
    }
  }

  // stage p = fw * g (f16 packed mul, RNE), odd-stride LDS plane
  for (int idx = tid; idx < 64 * 64; idx += 256) {
    int row = idx >> 6, c = idx & 63;       // c = 8B column index
    union { u64 u; half4 h; } a, b, p;
    a.u = *(const u64*)(fwh + (size_t)(R0 + row) * 256 + c * 4);
    b.u = *(const u64*)(gh  + (size_t)(R0 + row) * 256 + c * 4);
    p.h = a.h * b.h;                        // v_pk_mul_f16 x2
    p_pl[row * RSTR8 + c] = p.u;
  }
  lds_barrier();

  f32x4 hh[2][2], lh[2][2];
#pragma unroll
  for (int j = 0; j < 2; ++j)
#pragma unroll
    for (int jn = 0; jn < 2; ++jn) { hh[j][jn] = 0.0f; lh[j][jn] = 0.0f; }

#pragma unroll
  for (int kt = 0; kt < 8; ++kt) {
#pragma unroll
    for (int j = 0; j < 2; ++j) {
      const int row = 32 * rh + 16 * j + m;
      half8 pf = read_frag_h(p_pl, row, kt, q);
#pragma unroll
      for (int jn = 0; jn < 2; ++jn) {
        hh[j][jn] = mfma16f(pf, o_hi[kt][jn], hh[j][jn]);
        lh[j][jn] = mfma16f(pf, o_lo[kt][jn], lh[j][jn]);
      }
    }
  }

#pragma unroll
  for (int j = 0; j < 2; ++j) {
#pragma unroll
    for (int jn = 0; jn < 2; ++jn) {
      f32x4 acc = hh[j][jn] + lh[j][jn] * LO_UNSCALE;
#pragma unroll
      for (int r = 0; r < 4; ++r) {
        int row = R0 + 32 * rh + 16 * j + 4 * q + r;
        int l = row >> 7, b = row & 127;
        score[(size_t)b * 16384 + l * 64 + 16 * (2 * np + jn) + m] = acc[r];
      }
    }
  }
}

extern "C" void kernel_launch(void* const* d_in, const int* in_sizes, int n_in,
                              void* d_out, int out_size, void* d_ws, size_t ws_size,
                              hipStream_t stream) {
  (void)in_sizes; (void)n_in; (void)out_size; (void)ws_size;
  const int*   sent = (const int*)d_in[0];
  const float* emb  = (const float*)d_in[1];
  const float* T    = (const float*)d_in[2];
  const float* outm = (const float*)d_in[3];
  _Float16* fwh = (_Float16*)d_ws;                  // [L][B][S] f16, 16 MB
  _Float16* gh  = fwh + (size_t)LL * BB * SS;       // [L][B][S] f16, 16 MB

  hmm_chain<<<16, 512, 0, stream>>>(sent, emb, T, fwh, gh);
  hmm_score<<<512, 256, 0, stream>>>(fwh, gh, outm, (float*)d_out);
}

// Round 10
// 303.157 us; speedup vs baseline: 1.1209x; 1.1209x over previous
//
#include <hip/hip_runtime.h>
#include <hip/hip_bf16.h>

// IO-HMM fwd/bwd chain + projection for MI355X (gfx950).
// L=256 steps, B=128 batch, S=256 states, NL=64 labels.
//
// Kernel 1 (chain): 16 blocks (8 fwd, 8 bwd) x 1024 threads (16 waves).
//   R10: 16 waves x M=16 states/wave (was 8 x M=32). Same total MFMA and
//   LDS-write volume, but 4 waves/SIMD (was 2): the per-step barrier keeps
//   waves near-lockstep, so with 2 waves/SIMD the MFMA and VALU/LDS phases
//   alternated un-overlapped (R6-R9 plateau ~2350-2560 cyc/step vs 1241-cyc
//   MFMA issue floor). 4 waves/SIMD lets one wave's reads/epilogue hide
//   under another's MFMA. LDS reads double to 128 KB/step/CU (~1100 cyc),
//   still under the MFMA shadow.
//   T as f16 A-frags: a_hi=f16(T), a_lo=f16((T-hi)*2048) (scaled past f16
//   denormals); acc = hh + lh/2048 -> T to 2^-22.
//   Carry (16 b x 256 k) in LDS, double-buffered single-f16 plane, row
//   stride 67 x 8B (odd -> 0 bank conflicts, R5/R6-verified).
//   All carry packs are RNE casts -- NOT v_cvt_pkrtz: RTZ's -2^-12 bias
//   compounds coherently over 255 steps into ~6% shrink (R8: absmax 1792).
//   Tokens staged in LDS (stride 257); em prefetched one step ahead;
//   per-step barrier = s_waitcnt lgkmcnt(0); s_barrier (vmcnt in flight).
//   fw/g stored f16 (R6 proved range/precision fit; halves WRITE_SIZE).
// Kernel 2 (score): f16 end-to-end: p = fw*g via v_pk_mul_f16 (RNE), single
//   LDS plane, outm as f16 hi + scaled-lo (2 products).

typedef _Float16 half8 __attribute__((ext_vector_type(8)));
typedef _Float16 half4 __attribute__((ext_vector_type(4)));
typedef float    f32x4 __attribute__((ext_vector_type(4)));
typedef unsigned long long u64;

#define LL 256
#define BB 128
#define SS 256
#define BT 16
#define RSTR8 67   // LDS row stride in 8B units (ODD -> conflict-free, verified)
#define LO_SCALE 2048.0f
#define LO_UNSCALE 4.8828125e-4f

static __device__ __forceinline__ f32x4 mfma16f(half8 a, half8 b, f32x4 c) {
  return __builtin_amdgcn_mfma_f32_16x16x32_f16(a, b, c, 0, 0, 0);
}

// LDS-only barrier: order ds ops, leave vmcnt (global loads/stores) in flight.
static __device__ __forceinline__ void lds_barrier() {
  __asm__ __volatile__("s_waitcnt lgkmcnt(0)\n\ts_barrier" ::: "memory");
}

// Round-to-nearest-even f16 pack (NOT cvt_pkrtz -- see R8 erratum above).
static __device__ __forceinline__ u64 pack4(f32x4 v) {
  union { half4 h; u64 u; } x;
  x.h[0] = (_Float16)v[0];
  x.h[1] = (_Float16)v[1];
  x.h[2] = (_Float16)v[2];
  x.h[3] = (_Float16)v[3];
  return x.u;
}

static __device__ __forceinline__ half8 read_frag_h(const u64* plane, int m, int kt, int q) {
  const int o = m * RSTR8 + kt * 8 + q * 2;
  union { u64 u[2]; half8 v; } x;
  x.u[0] = plane[o];
  x.u[1] = plane[o + 1];
  return x.v;
}

__global__ __launch_bounds__(1024, 4)
void hmm_chain(const int* __restrict__ sent, const float* __restrict__ emb,
               const float* __restrict__ T, _Float16* __restrict__ fwh,
               _Float16* __restrict__ gh)
{
  __shared__ u64 s_carry[2][BT * RSTR8]; // [buf][row*stride], single f16 plane
  __shared__ int s_tok[BT * 257];        // [batch][l], stride 257

  const int tid  = threadIdx.x;
  const int lane = tid & 63;
  const int w    = tid >> 6;   // wave 0..15 -> states [16w, 16w+16)
  const int m    = lane & 15;  // A row-in-tile / B col (= batch)
  const int q    = lane >> 4;  // quad

  const int  bid = blockIdx.x;
  const bool fwd = (bid < 8);
  const int  bg0 = (fwd ? bid : bid - 8) * BT;
  _Float16* const obuf = fwd ? fwh : gh;
  const int  st  = 16 * w + 4 * q;       // this lane's first state

  // ---- stage sentence tokens ----
  for (int idx = tid; idx < BT * LL; idx += 1024) {
    int bb = idx >> 8, l2 = idx & 255;
    s_tok[bb * 257 + l2] = sent[(bg0 + bb) * LL + l2];
  }
  __syncthreads();

  // ---- load T fragments (A operand), f16 hi + scaled-lo: 16 frags = 64 regs
  half8 a_hi[8], a_lo[8];
#pragma unroll
  for (int kt = 0; kt < 8; ++kt) {
    const int r0 = 16 * w + m;           // state (M index)
    const int kb = 32 * kt + 8 * q;      // k base
    float v[8];
    if (fwd) {
      f32x4 f0 = *(const f32x4*)(T + r0 * 256 + kb);
      f32x4 f1 = *(const f32x4*)(T + r0 * 256 + kb + 4);
#pragma unroll
      for (int j = 0; j < 4; ++j) { v[j] = f0[j]; v[4 + j] = f1[j]; }
    } else {
#pragma unroll
      for (int j = 0; j < 8; ++j) v[j] = T[(kb + j) * 256 + r0]; // T^T
    }
    half8 hi, lo;
#pragma unroll
    for (int j = 0; j < 8; ++j) {
      _Float16 h = (_Float16)v[j];
      hi[j] = h;
      lo[j] = (_Float16)((v[j] - (float)h) * LO_SCALE);
    }
    a_hi[kt] = hi; a_lo[kt] = lo;
  }

  // ---- init carry at l0 + first-row store ----
  const int l0 = fwd ? 0 : (LL - 1);
  {
    const int tok0 = s_tok[m * 257 + l0];
    f32x4 e0 = *(const f32x4*)(emb + (size_t)tok0 * 256 + st);
    u64 pc = pack4(e0);                       // carry = em[l0] both dirs
    f32x4 one = 1.0f;
    u64 po = fwd ? pc : pack4(one);           // g[L-1] = 1
    *(u64*)(obuf + (size_t)(l0 * BB + bg0 + m) * SS + st) = po;
    s_carry[0][m * RSTR8 + 4 * w + q] = pc;
  }

  // ---- prefetch em for step 1 ----
  f32x4 em_pref;
  {
    const int l1 = fwd ? 1 : (LL - 2);
    const int tok1 = s_tok[m * 257 + l1];
    em_pref = *(const f32x4*)(emb + (size_t)tok1 * 256 + st);
  }
  __syncthreads();

  // ---- main chain ----
  for (int s = 1; s < LL; ++s) {
    const int l  = fwd ? s : (LL - 1) - s;
    const int rb = (s - 1) & 1, wb = s & 1;

    const u64* pr = &s_carry[rb][0];
    half8 bfr[8];
#pragma unroll
    for (int kt = 0; kt < 8; ++kt)
      bfr[kt] = read_frag_h(pr, m, kt, q);

    // consume prefetched em; issue next prefetch (token from LDS)
    f32x4 em_now = em_pref;
    {
      const int ln = fwd ? (s + 1 < LL ? s + 1 : LL - 1)
                         : ((LL - 2) - s > 0 ? (LL - 2) - s : 0);
      const int tokn = s_tok[m * 257 + ln];
      em_pref = *(const f32x4*)(emb + (size_t)tokn * 256 + st);
    }

    // 2 independent chains (x4 waves/SIMD = 8 in flight per SIMD)
    f32x4 hh = 0.0f, lh = 0.0f;
#pragma unroll
    for (int kt = 0; kt < 8; ++kt) {
      hh = mfma16f(a_hi[kt], bfr[kt], hh);
      lh = mfma16f(a_lo[kt], bfr[kt], lh);
    }
    f32x4 v  = hh + lh * LO_UNSCALE;   // pre-em matmul result
    f32x4 cn = v * em_now;             // new carry

    u64 p0 = pack4(cn);
    s_carry[wb][m * RSTR8 + 4 * w + q] = p0;
    u64 sv = fwd ? p0 : pack4(v);      // fwd stores fw[l]; bwd stores g[l]=v
    *(u64*)(obuf + (size_t)(l * BB + bg0 + m) * SS + st) = sv;
    lds_barrier();  // LDS ordering only; global stores/loads stay in flight
  }
}

__global__ __launch_bounds__(256, 2)
void hmm_score(const _Float16* __restrict__ fwh, const _Float16* __restrict__ gh,
               const float* __restrict__ outm, float* __restrict__ score)
{
  __shared__ u64 p_pl[64 * RSTR8];

  const int tid  = threadIdx.x;
  const int lane = tid & 63;
  const int w    = tid >> 6;
  const int rh   = w >> 1;     // row half: rows [32rh, 32rh+32)
  const int np   = w & 1;      // n-pair: n-tiles {2np, 2np+1}
  const int m    = lane & 15;
  const int q    = lane >> 4;
  const int R0   = blockIdx.x * 64;  // row = l*128 + b

  // out-matrix fragments, f16 hi + scaled lo, this wave's 2 n-tiles
  half8 o_hi[8][2], o_lo[8][2];
#pragma unroll
  for (int kt = 0; kt < 8; ++kt) {
#pragma unroll
    for (int jn = 0; jn < 2; ++jn) {
      half8 hi, lo;
#pragma unroll
      for (int j = 0; j < 8; ++j) {
        float vv = outm[(32 * kt + 8 * q + j) * 64 + 16 * (2 * np + jn) + m];
        _Float16 h = (_Float16)vv;
        hi[j] = h;
        lo[j] = (_Float16)((vv - (float)h) * LO_SCALE);
      }
      o_hi[kt][jn] = hi; o_lo[kt][jn] = lo;
    }
  }

  // stage p = fw * g (f16 packed mul, RNE), odd-stride LDS plane
  for (int idx = tid; idx < 64 * 64; idx += 256) {
    int row = idx >> 6, c = idx & 63;       // c = 8B column index
    union { u64 u; half4 h; } a, b, p;
    a.u = *(const u64*)(fwh + (size_t)(R0 + row) * 256 + c * 4);
    b.u = *(const u64*)(gh  + (size_t)(R0 + row) * 256 + c * 4);
    p.h = a.h * b.h;                        // v_pk_mul_f16 x2
    p_pl[row * RSTR8 + c] = p.u;
  }
  lds_barrier();

  f32x4 hh[2][2], lh[2][2];
#pragma unroll
  for (int j = 0; j < 2; ++j)
#pragma unroll
    for (int jn = 0; jn < 2; ++jn) { hh[j][jn] = 0.0f; lh[j][jn] = 0.0f; }

#pragma unroll
  for (int kt = 0; kt < 8; ++kt) {
#pragma unroll
    for (int j = 0; j < 2; ++j) {
      const int row = 32 * rh + 16 * j + m;
      half8 pf = read_frag_h(p_pl, row, kt, q);
#pragma unroll
      for (int jn = 0; jn < 2; ++jn) {
        hh[j][jn] = mfma16f(pf, o_hi[kt][jn], hh[j][jn]);
        lh[j][jn] = mfma16f(pf, o_lo[kt][jn], lh[j][jn]);
      }
    }
  }

#pragma unroll
  for (int j = 0; j < 2; ++j) {
#pragma unroll
    for (int jn = 0; jn < 2; ++jn) {
      f32x4 acc = hh[j][jn] + lh[j][jn] * LO_UNSCALE;
#pragma unroll
      for (int r = 0; r < 4; ++r) {
        int row = R0 + 32 * rh + 16 * j + 4 * q + r;
        int l = row >> 7, b = row & 127;
        score[(size_t)b * 16384 + l * 64 + 16 * (2 * np + jn) + m] = acc[r];
      }
    }
  }
}

extern "C" void kernel_launch(void* const* d_in, const int* in_sizes, int n_in,
                              void* d_out, int out_size, void* d_ws, size_t ws_size,
                              hipStream_t stream) {
  (void)in_sizes; (void)n_in; (void)out_size; (void)ws_size;
  const int*   sent = (const int*)d_in[0];
  const float* emb  = (const float*)d_in[1];
  const float* T    = (const float*)d_in[2];
  const float* outm = (const float*)d_in[3];
  _Float16* fwh = (_Float16*)d_ws;                  // [L][B][S] f16, 16 MB
  _Float16* gh  = fwh + (size_t)LL * BB * SS;       // [L][B][S] f16, 16 MB

  hmm_chain<<<16, 1024, 0, stream>>>(sent, emb, T, fwh, gh);
  hmm_score<<<512, 256, 0, stream>>>(fwh, gh, outm, (float*)d_out);
}

// Round 11
// 301.613 us; speedup vs baseline: 1.1266x; 1.0051x over previous
//
#include <hip/hip_runtime.h>
#include <hip/hip_bf16.h>

// IO-HMM fwd/bwd chain + projection for MI355X (gfx950).
// L=256 steps, B=128 batch, S=256 states, NL=64 labels.
//
// Kernel 1 (chain): UNCHANGED from R10 (measured 223 us, step ~2100 cyc,
//   VGPR 64, 0 conflicts): 16 blocks x 1024 threads (16 waves, 4/SIMD),
//   wave owns 16 states, T as f16 hi + scaled-lo A-frags (2 products ->
//   T to 2^-22; single-product f16 risks ~255x2^-12 coherent drift > 2%
//   threshold), carry = single f16 LDS plane, double-buffered, odd-8B row
//   stride (67), RNE packs only (R8: RTZ bias -> 6% shrink), lds-only
//   per-step barrier.
// Kernel 2 (score): R11 rewrite. R10's per-lane o-fragment build did 128
//   scattered scalar global loads/lane (~75 us for a ~10 us-roofline
//   kernel). Now outm is staged once per block into LDS transposed [n][k]
//   f16 (row stride 65x8B, odd -> conflict-free b64 frag reads), hi-only
//   (quantization ~2.4e-4 rel ~ 5 abs on score, under the measured absmax
//   floor of 64). 32 MFMA/wave, LDS 67.6 KB -> 2 blocks/CU.

typedef _Float16 half8 __attribute__((ext_vector_type(8)));
typedef _Float16 half4 __attribute__((ext_vector_type(4)));
typedef float    f32x4 __attribute__((ext_vector_type(4)));
typedef unsigned long long u64;

#define LL 256
#define BB 128
#define SS 256
#define BT 16
#define RSTR8 67   // carry/p-plane row stride in 8B units (ODD -> conflict-free)
#define RSTRO 65   // o-plane row stride in 8B units (ODD -> conflict-free)
#define LO_SCALE 2048.0f
#define LO_UNSCALE 4.8828125e-4f

static __device__ __forceinline__ f32x4 mfma16f(half8 a, half8 b, f32x4 c) {
  return __builtin_amdgcn_mfma_f32_16x16x32_f16(a, b, c, 0, 0, 0);
}

// LDS-only barrier: order ds ops, leave vmcnt (global loads/stores) in flight.
static __device__ __forceinline__ void lds_barrier() {
  __asm__ __volatile__("s_waitcnt lgkmcnt(0)\n\ts_barrier" ::: "memory");
}

// Round-to-nearest-even f16 pack (NOT cvt_pkrtz -- RTZ bias compounds over
// the 255-step chain into ~6% coherent shrink; R8 erratum).
static __device__ __forceinline__ u64 pack4(f32x4 v) {
  union { half4 h; u64 u; } x;
  x.h[0] = (_Float16)v[0];
  x.h[1] = (_Float16)v[1];
  x.h[2] = (_Float16)v[2];
  x.h[3] = (_Float16)v[3];
  return x.u;
}

// 16B logical fragment as two b64 reads (8B-aligned odd-stride layout).
static __device__ __forceinline__ half8 read_frag_s(const u64* plane, int row,
                                                    int kt, int q, int stride8) {
  const int o = row * stride8 + kt * 8 + q * 2;
  union { u64 u[2]; half8 v; } x;
  x.u[0] = plane[o];
  x.u[1] = plane[o + 1];
  return x.v;
}

__global__ __launch_bounds__(1024, 4)
void hmm_chain(const int* __restrict__ sent, const float* __restrict__ emb,
               const float* __restrict__ T, _Float16* __restrict__ fwh,
               _Float16* __restrict__ gh)
{
  __shared__ u64 s_carry[2][BT * RSTR8]; // [buf][row*stride], single f16 plane
  __shared__ int s_tok[BT * 257];        // [batch][l], stride 257

  const int tid  = threadIdx.x;
  const int lane = tid & 63;
  const int w    = tid >> 6;   // wave 0..15 -> states [16w, 16w+16)
  const int m    = lane & 15;  // A row-in-tile / B col (= batch)
  const int q    = lane >> 4;  // quad

  const int  bid = blockIdx.x;
  const bool fwd = (bid < 8);
  const int  bg0 = (fwd ? bid : bid - 8) * BT;
  _Float16* const obuf = fwd ? fwh : gh;
  const int  st  = 16 * w + 4 * q;       // this lane's first state

  // ---- stage sentence tokens ----
  for (int idx = tid; idx < BT * LL; idx += 1024) {
    int bb = idx >> 8, l2 = idx & 255;
    s_tok[bb * 257 + l2] = sent[(bg0 + bb) * LL + l2];
  }
  __syncthreads();

  // ---- load T fragments (A operand), f16 hi + scaled-lo: 16 frags = 64 regs
  half8 a_hi[8], a_lo[8];
#pragma unroll
  for (int kt = 0; kt < 8; ++kt) {
    const int r0 = 16 * w + m;           // state (M index)
    const int kb = 32 * kt + 8 * q;      // k base
    float v[8];
    if (fwd) {
      f32x4 f0 = *(const f32x4*)(T + r0 * 256 + kb);
      f32x4 f1 = *(const f32x4*)(T + r0 * 256 + kb + 4);
#pragma unroll
      for (int j = 0; j < 4; ++j) { v[j] = f0[j]; v[4 + j] = f1[j]; }
    } else {
#pragma unroll
      for (int j = 0; j < 8; ++j) v[j] = T[(kb + j) * 256 + r0]; // T^T
    }
    half8 hi, lo;
#pragma unroll
    for (int j = 0; j < 8; ++j) {
      _Float16 h = (_Float16)v[j];
      hi[j] = h;
      lo[j] = (_Float16)((v[j] - (float)h) * LO_SCALE);
    }
    a_hi[kt] = hi; a_lo[kt] = lo;
  }

  // ---- init carry at l0 + first-row store ----
  const int l0 = fwd ? 0 : (LL - 1);
  {
    const int tok0 = s_tok[m * 257 + l0];
    f32x4 e0 = *(const f32x4*)(emb + (size_t)tok0 * 256 + st);
    u64 pc = pack4(e0);                       // carry = em[l0] both dirs
    f32x4 one = 1.0f;
    u64 po = fwd ? pc : pack4(one);           // g[L-1] = 1
    *(u64*)(obuf + (size_t)(l0 * BB + bg0 + m) * SS + st) = po;
    s_carry[0][m * RSTR8 + 4 * w + q] = pc;
  }

  // ---- prefetch em for step 1 ----
  f32x4 em_pref;
  {
    const int l1 = fwd ? 1 : (LL - 2);
    const int tok1 = s_tok[m * 257 + l1];
    em_pref = *(const f32x4*)(emb + (size_t)tok1 * 256 + st);
  }
  __syncthreads();

  // ---- main chain ----
  for (int s = 1; s < LL; ++s) {
    const int l  = fwd ? s : (LL - 1) - s;
    const int rb = (s - 1) & 1, wb = s & 1;

    const u64* pr = &s_carry[rb][0];
    half8 bfr[8];
#pragma unroll
    for (int kt = 0; kt < 8; ++kt)
      bfr[kt] = read_frag_s(pr, m, kt, q, RSTR8);

    // consume prefetched em; issue next prefetch (token from LDS)
    f32x4 em_now = em_pref;
    {
      const int ln = fwd ? (s + 1 < LL ? s + 1 : LL - 1)
                         : ((LL - 2) - s > 0 ? (LL - 2) - s : 0);
      const int tokn = s_tok[m * 257 + ln];
      em_pref = *(const f32x4*)(emb + (size_t)tokn * 256 + st);
    }

    // 2 independent chains (x4 waves/SIMD = 8 in flight per SIMD)
    f32x4 hh = 0.0f, lh = 0.0f;
#pragma unroll
    for (int kt = 0; kt < 8; ++kt) {
      hh = mfma16f(a_hi[kt], bfr[kt], hh);
      lh = mfma16f(a_lo[kt], bfr[kt], lh);
    }
    f32x4 v  = hh + lh * LO_UNSCALE;   // pre-em matmul result
    f32x4 cn = v * em_now;             // new carry

    u64 p0 = pack4(cn);
    s_carry[wb][m * RSTR8 + 4 * w + q] = p0;
    u64 sv = fwd ? p0 : pack4(v);      // fwd stores fw[l]; bwd stores g[l]=v
    *(u64*)(obuf + (size_t)(l * BB + bg0 + m) * SS + st) = sv;
    lds_barrier();  // LDS ordering only; global stores/loads stay in flight
  }
}

__global__ __launch_bounds__(256, 2)
void hmm_score(const _Float16* __restrict__ fwh, const _Float16* __restrict__ gh,
               const float* __restrict__ outm, float* __restrict__ score)
{
  __shared__ u64 p_pl[64 * RSTR8];   // p = fw*g, [row][k] f16, 34,304 B
  __shared__ u64 o_pl[64 * RSTRO];   // outm^T,   [n][k]  f16, 33,280 B

  const int tid  = threadIdx.x;
  const int lane = tid & 63;
  const int w    = tid >> 6;
  const int rh   = w >> 1;     // row half: rows [32rh, 32rh+32)
  const int np   = w & 1;      // n-pair: n-tiles {2np, 2np+1}
  const int m    = lane & 15;
  const int q    = lane >> 4;
  const int R0   = blockIdx.x * 64;  // row = l*128 + b

  // ---- stage outm -> o_pl[n][k] f16 (RNE, hi only), coalesced f32x4 loads
  {
    _Float16* o_h = (_Float16*)o_pl;
    for (int i = tid; i < 4096; i += 256) {
      f32x4 v = *(const f32x4*)(outm + i * 4);   // flat = k*64+n
      int k = i >> 4, n0 = (i & 15) * 4;
#pragma unroll
      for (int r = 0; r < 4; ++r)
        o_h[(n0 + r) * (RSTRO * 4) + k] = (_Float16)v[r];
    }
  }

  // ---- stage p = fw * g (f16 packed mul, RNE) ----
  for (int idx = tid; idx < 64 * 64; idx += 256) {
    int row = idx >> 6, c = idx & 63;       // c = 8B column index
    union { u64 u; half4 h; } a, b, p;
    a.u = *(const u64*)(fwh + (size_t)(R0 + row) * 256 + c * 4);
    b.u = *(const u64*)(gh  + (size_t)(R0 + row) * 256 + c * 4);
    p.h = a.h * b.h;                        // v_pk_mul_f16 x2
    p_pl[row * RSTR8 + c] = p.u;
  }
  lds_barrier();

  f32x4 acc[2][2];
#pragma unroll
  for (int j = 0; j < 2; ++j)
#pragma unroll
    for (int jn = 0; jn < 2; ++jn) acc[j][jn] = 0.0f;

#pragma unroll
  for (int kt = 0; kt < 8; ++kt) {
    half8 of[2];
#pragma unroll
    for (int jn = 0; jn < 2; ++jn)
      of[jn] = read_frag_s(o_pl, 16 * (2 * np + jn) + m, kt, q, RSTRO);
#pragma unroll
    for (int j = 0; j < 2; ++j) {
      half8 pf = read_frag_s(p_pl, 32 * rh + 16 * j + m, kt, q, RSTR8);
#pragma unroll
      for (int jn = 0; jn < 2; ++jn)
        acc[j][jn] = mfma16f(pf, of[jn], acc[j][jn]);
    }
  }

#pragma unroll
  for (int j = 0; j < 2; ++j) {
#pragma unroll
    for (int jn = 0; jn < 2; ++jn) {
#pragma unroll
      for (int r = 0; r < 4; ++r) {
        int row = R0 + 32 * rh + 16 * j + 4 * q + r;
        int l = row >> 7, b = row & 127;
        score[(size_t)b * 16384 + l * 64 + 16 * (2 * np + jn) + m] = acc[j][jn][r];
      }
    }
  }
}

extern "C" void kernel_launch(void* const* d_in, const int* in_sizes, int n_in,
                              void* d_out, int out_size, void* d_ws, size_t ws_size,
                              hipStream_t stream) {
  (void)in_sizes; (void)n_in; (void)out_size; (void)ws_size;
  const int*   sent = (const int*)d_in[0];
  const float* emb  = (const float*)d_in[1];
  const float* T    = (const float*)d_in[2];
  const float* outm = (const float*)d_in[3];
  _Float16* fwh = (_Float16*)d_ws;                  // [L][B][S] f16, 16 MB
  _Float16* gh  = fwh + (size_t)LL * BB * SS;       // [L][B][S] f16, 16 MB

  hmm_chain<<<16, 1024, 0, stream>>>(sent, emb, T, fwh, gh);
  hmm_score<<<512, 256, 0, stream>>>(fwh, gh, outm, (float*)d_out);
}

// Round 12
// 293.826 us; speedup vs baseline: 1.1565x; 1.0265x over previous
//
#include <hip/hip_runtime.h>
#include <hip/hip_bf16.h>

// IO-HMM fwd/bwd chain + projection for MI355X (gfx950).
// L=256 steps, B=128 batch, S=256 states, NL=64 labels.
//
// Kernel 1 (chain): R10 structure, R12 precision change: T held as SINGLE
//   f16 A-frag (was hi + scaled-lo). Rationale: absmax pinned at the 64.0
//   harness floor for 9 rounds through every quantization change; f16 T's
//   fixed-pattern 2^-12 RMS error accumulates ~sqrt(255)*2^-12 ~ 0.4-1%
//   under a mixing chain (unbiased, unlike R8's RTZ bias which DID compound
//   coherently to 6%). Halves chain MFMA (8/wave/step) and trims the
//   combine VALU. REVERT to 2-product if absmax > 396.8.
//   16 blocks (8 fwd, 8 bwd) x 1024 threads (16 waves, 4/SIMD -- R10
//   measured win over 2/SIMD), wave owns 16 states, carry = single f16 LDS
//   plane, double-buffered, odd-8B row stride 67 (0 conflicts, verified),
//   RNE packs only, lds-only per-step barrier, em prefetched 1 step ahead.
//   fw/g stored f16.
// Kernel 2 (score): R11 version (outm staged once per block to LDS [n][k]
//   f16, odd stride 65; p = fw*g via v_pk_mul_f16; 32 MFMA/wave). Note:
//   seven score variants R3-R11 left the chain<->total gap at 74-80 us ->
//   the gap is timed-region overhead, not this kernel.

typedef _Float16 half8 __attribute__((ext_vector_type(8)));
typedef _Float16 half4 __attribute__((ext_vector_type(4)));
typedef float    f32x4 __attribute__((ext_vector_type(4)));
typedef unsigned long long u64;

#define LL 256
#define BB 128
#define SS 256
#define BT 16
#define RSTR8 67   // carry/p-plane row stride in 8B units (ODD -> conflict-free)
#define RSTRO 65   // o-plane row stride in 8B units (ODD -> conflict-free)

static __device__ __forceinline__ f32x4 mfma16f(half8 a, half8 b, f32x4 c) {
  return __builtin_amdgcn_mfma_f32_16x16x32_f16(a, b, c, 0, 0, 0);
}

// LDS-only barrier: order ds ops, leave vmcnt (global loads/stores) in flight.
static __device__ __forceinline__ void lds_barrier() {
  __asm__ __volatile__("s_waitcnt lgkmcnt(0)\n\ts_barrier" ::: "memory");
}

// Round-to-nearest-even f16 pack (NOT cvt_pkrtz -- RTZ bias compounds over
// the 255-step chain into ~6% coherent shrink; R8 erratum).
static __device__ __forceinline__ u64 pack4(f32x4 v) {
  union { half4 h; u64 u; } x;
  x.h[0] = (_Float16)v[0];
  x.h[1] = (_Float16)v[1];
  x.h[2] = (_Float16)v[2];
  x.h[3] = (_Float16)v[3];
  return x.u;
}

// 16B logical fragment as two b64 reads (8B-aligned odd-stride layout).
static __device__ __forceinline__ half8 read_frag_s(const u64* plane, int row,
                                                    int kt, int q, int stride8) {
  const int o = row * stride8 + kt * 8 + q * 2;
  union { u64 u[2]; half8 v; } x;
  x.u[0] = plane[o];
  x.u[1] = plane[o + 1];
  return x.v;
}

__global__ __launch_bounds__(1024, 4)
void hmm_chain(const int* __restrict__ sent, const float* __restrict__ emb,
               const float* __restrict__ T, _Float16* __restrict__ fwh,
               _Float16* __restrict__ gh)
{
  __shared__ u64 s_carry[2][BT * RSTR8]; // [buf][row*stride], single f16 plane
  __shared__ int s_tok[BT * 257];        // [batch][l], stride 257

  const int tid  = threadIdx.x;
  const int lane = tid & 63;
  const int w    = tid >> 6;   // wave 0..15 -> states [16w, 16w+16)
  const int m    = lane & 15;  // A row-in-tile / B col (= batch)
  const int q    = lane >> 4;  // quad

  const int  bid = blockIdx.x;
  const bool fwd = (bid < 8);
  const int  bg0 = (fwd ? bid : bid - 8) * BT;
  _Float16* const obuf = fwd ? fwh : gh;
  const int  st  = 16 * w + 4 * q;       // this lane's first state

  // ---- stage sentence tokens ----
  for (int idx = tid; idx < BT * LL; idx += 1024) {
    int bb = idx >> 8, l2 = idx & 255;
    s_tok[bb * 257 + l2] = sent[(bg0 + bb) * LL + l2];
  }
  __syncthreads();

  // ---- load T fragments (A operand), single f16: 8 frags = 32 regs
  half8 a_hi[8];
#pragma unroll
  for (int kt = 0; kt < 8; ++kt) {
    const int r0 = 16 * w + m;           // state (M index)
    const int kb = 32 * kt + 8 * q;      // k base
    float v[8];
    if (fwd) {
      f32x4 f0 = *(const f32x4*)(T + r0 * 256 + kb);
      f32x4 f1 = *(const f32x4*)(T + r0 * 256 + kb + 4);
#pragma unroll
      for (int j = 0; j < 4; ++j) { v[j] = f0[j]; v[4 + j] = f1[j]; }
    } else {
#pragma unroll
      for (int j = 0; j < 8; ++j) v[j] = T[(kb + j) * 256 + r0]; // T^T
    }
    half8 hi;
#pragma unroll
    for (int j = 0; j < 8; ++j) hi[j] = (_Float16)v[j];   // RNE
    a_hi[kt] = hi;
  }

  // ---- init carry at l0 + first-row store ----
  const int l0 = fwd ? 0 : (LL - 1);
  {
    const int tok0 = s_tok[m * 257 + l0];
    f32x4 e0 = *(const f32x4*)(emb + (size_t)tok0 * 256 + st);
    u64 pc = pack4(e0);                       // carry = em[l0] both dirs
    f32x4 one = 1.0f;
    u64 po = fwd ? pc : pack4(one);           // g[L-1] = 1
    *(u64*)(obuf + (size_t)(l0 * BB + bg0 + m) * SS + st) = po;
    s_carry[0][m * RSTR8 + 4 * w + q] = pc;
  }

  // ---- prefetch em for step 1 ----
  f32x4 em_pref;
  {
    const int l1 = fwd ? 1 : (LL - 2);
    const int tok1 = s_tok[m * 257 + l1];
    em_pref = *(const f32x4*)(emb + (size_t)tok1 * 256 + st);
  }
  __syncthreads();

  // ---- main chain ----
  for (int s = 1; s < LL; ++s) {
    const int l  = fwd ? s : (LL - 1) - s;
    const int rb = (s - 1) & 1, wb = s & 1;

    const u64* pr = &s_carry[rb][0];
    half8 bfr[8];
#pragma unroll
    for (int kt = 0; kt < 8; ++kt)
      bfr[kt] = read_frag_s(pr, m, kt, q, RSTR8);

    // consume prefetched em; issue next prefetch (token from LDS)
    f32x4 em_now = em_pref;
    {
      const int ln = fwd ? (s + 1 < LL ? s + 1 : LL - 1)
                         : ((LL - 2) - s > 0 ? (LL - 2) - s : 0);
      const int tokn = s_tok[m * 257 + ln];
      em_pref = *(const f32x4*)(emb + (size_t)tokn * 256 + st);
    }

    // single-product f16 matmul (8 MFMA/wave/step)
    f32x4 hh = 0.0f;
#pragma unroll
    for (int kt = 0; kt < 8; ++kt)
      hh = mfma16f(a_hi[kt], bfr[kt], hh);
    f32x4 v  = hh;                     // pre-em matmul result
    f32x4 cn = v * em_now;             // new carry

    u64 p0 = pack4(cn);
    s_carry[wb][m * RSTR8 + 4 * w + q] = p0;
    u64 sv = fwd ? p0 : pack4(v);      // fwd stores fw[l]; bwd stores g[l]=v
    *(u64*)(obuf + (size_t)(l * BB + bg0 + m) * SS + st) = sv;
    lds_barrier();  // LDS ordering only; global stores/loads stay in flight
  }
}

__global__ __launch_bounds__(256, 2)
void hmm_score(const _Float16* __restrict__ fwh, const _Float16* __restrict__ gh,
               const float* __restrict__ outm, float* __restrict__ score)
{
  __shared__ u64 p_pl[64 * RSTR8];   // p = fw*g, [row][k] f16
  __shared__ u64 o_pl[64 * RSTRO];   // outm^T,   [n][k]  f16

  const int tid  = threadIdx.x;
  const int lane = tid & 63;
  const int w    = tid >> 6;
  const int rh   = w >> 1;     // row half: rows [32rh, 32rh+32)
  const int np   = w & 1;      // n-pair: n-tiles {2np, 2np+1}
  const int m    = lane & 15;
  const int q    = lane >> 4;
  const int R0   = blockIdx.x * 64;  // row = l*128 + b

  // ---- stage outm -> o_pl[n][k] f16 (RNE, hi only), coalesced f32x4 loads
  {
    _Float16* o_h = (_Float16*)o_pl;
    for (int i = tid; i < 4096; i += 256) {
      f32x4 v = *(const f32x4*)(outm + i * 4);   // flat = k*64+n
      int k = i >> 4, n0 = (i & 15) * 4;
#pragma unroll
      for (int r = 0; r < 4; ++r)
        o_h[(n0 + r) * (RSTRO * 4) + k] = (_Float16)v[r];
    }
  }

  // ---- stage p = fw * g (f16 packed mul, RNE) ----
  for (int idx = tid; idx < 64 * 64; idx += 256) {
    int row = idx >> 6, c = idx & 63;       // c = 8B column index
    union { u64 u; half4 h; } a, b, p;
    a.u = *(const u64*)(fwh + (size_t)(R0 + row) * 256 + c * 4);
    b.u = *(const u64*)(gh  + (size_t)(R0 + row) * 256 + c * 4);
    p.h = a.h * b.h;                        // v_pk_mul_f16 x2
    p_pl[row * RSTR8 + c] = p.u;
  }
  lds_barrier();

  f32x4 acc[2][2];
#pragma unroll
  for (int j = 0; j < 2; ++j)
#pragma unroll
    for (int jn = 0; jn < 2; ++jn) acc[j][jn] = 0.0f;

#pragma unroll
  for (int kt = 0; kt < 8; ++kt) {
    half8 of[2];
#pragma unroll
    for (int jn = 0; jn < 2; ++jn)
      of[jn] = read_frag_s(o_pl, 16 * (2 * np + jn) + m, kt, q, RSTRO);
#pragma unroll
    for (int j = 0; j < 2; ++j) {
      half8 pf = read_frag_s(p_pl, 32 * rh + 16 * j + m, kt, q, RSTR8);
#pragma unroll
      for (int jn = 0; jn < 2; ++jn)
        acc[j][jn] = mfma16f(pf, of[jn], acc[j][jn]);
    }
  }

#pragma unroll
  for (int j = 0; j < 2; ++j) {
#pragma unroll
    for (int jn = 0; jn < 2; ++jn) {
#pragma unroll
      for (int r = 0; r < 4; ++r) {
        int row = R0 + 32 * rh + 16 * j + 4 * q + r;
        int l = row >> 7, b = row & 127;
        score[(size_t)b * 16384 + l * 64 + 16 * (2 * np + jn) + m] = acc[j][jn][r];
      }
    }
  }
}

extern "C" void kernel_launch(void* const* d_in, const int* in_sizes, int n_in,
                              void* d_out, int out_size, void* d_ws, size_t ws_size,
                              hipStream_t stream) {
  (void)in_sizes; (void)n_in; (void)out_size; (void)ws_size;
  const int*   sent = (const int*)d_in[0];
  const float* emb  = (const float*)d_in[1];
  const float* T    = (const float*)d_in[2];
  const float* outm = (const float*)d_in[3];
  _Float16* fwh = (_Float16*)d_ws;                  // [L][B][S] f16, 16 MB
  _Float16* gh  = fwh + (size_t)LL * BB * SS;       // [L][B][S] f16, 16 MB

  hmm_chain<<<16, 1024, 0, stream>>>(sent, emb, T, fwh, gh);
  hmm_score<<<512, 256, 0, stream>>>(fwh, gh, outm, (float*)d_out);
}